// Round 13
// baseline (445.998 us; speedup 1.0000x reference)
//
#include <hip/hip_runtime.h>
#include <hip/hip_bf16.h>
#include <cstdint>
#include <cstddef>

// ---------------------------------------------------------------------------
// ImprovedCrossScaleGNN on MI355X (gfx950).
// Inputs float32 + int32, output float32. bf16 MFMA GEMMs, f32 stats.
// R23->R24: mha obf_s stride 144 -> 136 shorts. At 288B/row the q-group
// delta (1152B) is =0 mod the 128B bank cycle -> 4-way write conflicts and
// 2x-slow ofrag b128 reads (400K SQ_LDS_BANK_CONFLICT/dispatch). 272B rows
// give q-delta=16 banks (2-way, free) and perfectly-spread b128 reads.
// Bit-identical values, relocated in LDS. All prior structure kept.
// ---------------------------------------------------------------------------

typedef __attribute__((ext_vector_type(8))) short bf16x8;
typedef __attribute__((ext_vector_type(4))) float f32x4;

#define EPSV 1e-5f

__device__ __forceinline__ float b2f(unsigned short u) {
    union { unsigned int i; float f; } x; x.i = ((unsigned int)u) << 16; return x.f;
}
__device__ __forceinline__ unsigned short f2b(float f) {
    union { float f; unsigned int i; } x; x.f = f;
    unsigned int i = x.i;
    return (unsigned short)((i + 0x7fffu + ((i >> 16) & 1u)) >> 16);
}

// ---------------- prep: weights -> fragment-linear bf16 + feature casts ------
// Trailing range: edge-degree count, 4 contiguous edges per thread (ILP).
__global__ void prep_kernel(const float* __restrict__ node_W, const float* __restrict__ comm_W,
                            const float* __restrict__ cls_W1, const float* __restrict__ attn_in_w,
                            const float* __restrict__ attn_out_w, const float* __restrict__ comm_feat,
                            const float* __restrict__ node_feat,
                            unsigned short* __restrict__ WtN, unsigned short* __restrict__ WtC,
                            unsigned short* __restrict__ W1t, unsigned short* __restrict__ WinB,
                            unsigned short* __restrict__ WoutB, unsigned short* __restrict__ cfb,
                            unsigned short* __restrict__ nfb, int nC128, int nN128,
                            const int* __restrict__ ndst, int* __restrict__ cnt_n, int nE,
                            const int* __restrict__ cdst, int* __restrict__ cnt_c, int cE) {
    int idx = blockIdx.x * 256 + threadIdx.x;
    if (idx < 49152) {  // node_W [3][128][128] (W[k][col])
        int l = idx >> 14, e = idx & 16383;
        int j = e & 7, lane = (e >> 3) & 63, kc = (e >> 9) & 3, t = e >> 11;
        int col = t * 16 + (lane & 15);
        int k = (lane >> 4) * 8 + kc * 32 + j;
        WtN[idx] = f2b(node_W[l * 16384 + k * 128 + col]); return;
    }
    idx -= 49152;
    if (idx < 49152) {  // comm_W
        int l = idx >> 14, e = idx & 16383;
        int j = e & 7, lane = (e >> 3) & 63, kc = (e >> 9) & 3, t = e >> 11;
        int col = t * 16 + (lane & 15);
        int k = (lane >> 4) * 8 + kc * 32 + j;
        WtC[idx] = f2b(comm_W[l * 16384 + k * 128 + col]); return;
    }
    idx -= 49152;
    if (idx < 8192) {   // cls_W1 [128][64] (W[k][col]), 4 tiles
        int e = idx;
        int j = e & 7, lane = (e >> 3) & 63, kc = (e >> 9) & 3, t = e >> 11;
        int col = t * 16 + (lane & 15);
        int k = (lane >> 4) * 8 + kc * 32 + j;
        W1t[idx] = f2b(cls_W1[k * 64 + col]); return;
    }
    idx -= 8192;
    if (idx < 49152) {  // attn_in_w [384][128] = Bt[col][k], 24 tiles
        int e = idx;
        int j = e & 7, lane = (e >> 3) & 63, kc = (e >> 9) & 3, t = e >> 11;
        int col = t * 16 + (lane & 15);
        int k = (lane >> 4) * 8 + kc * 32 + j;
        WinB[idx] = f2b(attn_in_w[col * 128 + k]); return;
    }
    idx -= 49152;
    if (idx < 16384) {  // attn_out_w [128][128] = Bt[col][k], 8 tiles
        int e = idx;
        int j = e & 7, lane = (e >> 3) & 63, kc = (e >> 9) & 3, t = e >> 11;
        int col = t * 16 + (lane & 15);
        int k = (lane >> 4) * 8 + kc * 32 + j;
        WoutB[idx] = f2b(attn_out_w[col * 128 + k]); return;
    }
    idx -= 16384;
    if (idx < nC128) { cfb[idx] = f2b(comm_feat[idx]); return; }
    idx -= nC128;
    if (idx < nN128) { nfb[idx] = f2b(node_feat[idx]); return; }
    idx -= nN128;
    // count region: 4 contiguous edges per thread (independent atomics)
    long eg = (long)idx * 4;
    if (eg < (long)nE + cE) {
        int dd[4]; int wh[4];
#pragma unroll
        for (int k = 0; k < 4; ++k) {
            long e = eg + k;
            if (e < nE) { dd[k] = ndst[e]; wh[k] = 0; }
            else if (e - nE < cE) { dd[k] = cdst[e - nE]; wh[k] = 1; }
            else wh[k] = -1;
        }
#pragma unroll
        for (int k = 0; k < 4; ++k) {
            if (wh[k] == 0) atomicAdd(&cnt_n[dd[k]], 1);
            else if (wh[k] == 1) atomicAdd(&cnt_c[dd[k]], 1);
        }
    }
}

// scans PADDED counts: ceil8(cnt). Extra trailing blocks compute dinv.
// bsum stays RAW (per-block totals); scan_add computes its prefix inline.
__global__ void scan_block_dual(const int* __restrict__ cnt_n, int* __restrict__ rs_n,
                                int* __restrict__ bsum_n, int nN, int nbN,
                                const int* __restrict__ cnt_c, int* __restrict__ rs_c,
                                int* __restrict__ bsum_c, int nC,
                                float* __restrict__ di_n, float* __restrict__ di_c) {
    __shared__ int tmp[2048];
    int nbC = (nC + 1023) >> 10;
    int extra = (int)blockIdx.x - (nbN + nbC);
    if (extra >= 0) {  // dinv region
        int g = extra * 1024 + (int)threadIdx.x;
        if (g < nN) di_n[g] = rsqrtf((float)cnt_n[g] + 1.0f);
        else { int gc = g - nN; if (gc < nC) di_c[gc] = rsqrtf((float)cnt_c[gc] + 1.0f); }
        return;
    }
    const int* cnt; int* excl; int* bsum; int n, lb;
    if ((int)blockIdx.x < nbN) { cnt = cnt_n; excl = rs_n; bsum = bsum_n; n = nN; lb = blockIdx.x; }
    else { cnt = cnt_c; excl = rs_c; bsum = bsum_c; n = nC; lb = blockIdx.x - nbN; }
    int tid = threadIdx.x;
    int gid = lb * 1024 + tid;
    int v = (gid < n) ? ((cnt[gid] + 7) & ~7) : 0;
    int buf = 0;
    tmp[tid] = v;
    __syncthreads();
    for (int d = 1; d < 1024; d <<= 1) {
        int t = tmp[buf * 1024 + tid];
        int add = (tid >= d) ? tmp[buf * 1024 + tid - d] : 0;
        tmp[(1 - buf) * 1024 + tid] = t + add;
        buf = 1 - buf;
        __syncthreads();
    }
    int inc = tmp[buf * 1024 + tid];
    if (gid < n) excl[gid] = inc - v;
    if (tid == 1023) bsum[lb] = inc;
}

// finalize rs from RAW bsum (inline prefix) AND preload cur = rs.
__global__ void scan_add_dual(int* __restrict__ rs_n, const int* __restrict__ bsum_n,
                              int* __restrict__ cur_n, int nN,
                              int* __restrict__ rs_c, const int* __restrict__ bsum_c,
                              int* __restrict__ cur_c, int nC) {
    int gid = blockIdx.x * 256 + threadIdx.x;
    if (gid < nN) {
        int lb = gid >> 10;
        int p = 0;
        for (int i = 0; i < lb; ++i) p += bsum_n[i];
        int v = rs_n[gid] + p;
        rs_n[gid] = v; cur_n[gid] = v;
    } else {
        int g = gid - nN;
        if (g < nC) {
            int lb = g >> 10;
            int p = 0;
            for (int i = 0; i < lb; ++i) p += bsum_c[i];
            int v = rs_c[g] + p;
            rs_c[g] = v; cur_c[g] = v;
        }
    }
}

// ---------------- MFMA GEMM wave body: 16 rows x 128 cols, bf16 out ----------
__device__ __forceinline__ void gemm_wave_128(const unsigned short* __restrict__ A,
                                              const unsigned short* __restrict__ Bt,
                                              const float* __restrict__ di,
                                              unsigned short* __restrict__ D,
                                              int M, int m0, int lane) {
    int r = lane & 15, q = lane >> 4;
    int arow = m0 + r; if (arow >= M) arow = M - 1;
    const unsigned short* ap = A + (size_t)arow * 128 + q * 8;
    bf16x8 afrag[4];
#pragma unroll
    for (int kc = 0; kc < 4; ++kc)
        afrag[kc] = *(const bf16x8*)(const void*)(ap + kc * 32);
    float dsc[4];
#pragma unroll
    for (int t = 0; t < 4; ++t) {
        int row = m0 + q * 4 + t; if (row >= M) row = M - 1;
        dsc[t] = di[row];
    }
#pragma unroll
    for (int tt = 0; tt < 8; ++tt) {
        f32x4 acc = {0.f, 0.f, 0.f, 0.f};
#pragma unroll
        for (int kc = 0; kc < 4; ++kc) {
            bf16x8 bfrag = *(const bf16x8*)(const void*)(Bt + (((size_t)tt * 4 + kc) << 9) + lane * 8);
            acc = __builtin_amdgcn_mfma_f32_16x16x32_bf16(afrag[kc], bfrag, acc, 0, 0, 0);
        }
        int n0 = tt * 16;
#pragma unroll
        for (int t = 0; t < 4; ++t) {
            int row = m0 + q * 4 + t;
            if (row < M) D[(size_t)row * 128 + n0 + r] = f2b(acc[t] * dsc[t]);
        }
    }
}

// layer-0 gemm + CSR fill merged. Fill: 4 contiguous edges per thread;
// phase 1 issues 4 independent atomicAdds (slot alloc), phase 2 does the 4
// nontemporal ushort stores of s+1 (0 = pad sentinel from zero prefill).
__global__ __launch_bounds__(256) void gemm_fill_kernel(
    const unsigned short* __restrict__ A0, const unsigned short* __restrict__ Bt0,
    const float* __restrict__ di0, unsigned short* __restrict__ D0, int M0, int blocksA,
    const unsigned short* __restrict__ A1, const unsigned short* __restrict__ Bt1,
    const float* __restrict__ di1, unsigned short* __restrict__ D1, int M1, int blocksB,
    const int* __restrict__ ns, const int* __restrict__ ndst,
    int* __restrict__ cur_n, unsigned short* __restrict__ csrc_n, int nE,
    const int* __restrict__ cs, const int* __restrict__ cdst,
    int* __restrict__ cur_c, unsigned short* __restrict__ csrc_c, int cE) {
    int blk = blockIdx.x;
    if (blk < blocksA + blocksB) {
        const unsigned short *A, *Bt; const float* di; unsigned short* D; int M, lb;
        if (blk < blocksA) { A = A0; Bt = Bt0; di = di0; D = D0; M = M0; lb = blk; }
        else { A = A1; Bt = Bt1; di = di1; D = D1; M = M1; lb = blk - blocksA; }
        int m0 = (lb * 4 + (int)(threadIdx.x >> 6)) * 16;
        if (m0 >= M) return;
        gemm_wave_128(A, Bt, di, D, M, m0, threadIdx.x & 63);
        return;
    }
    long eg = ((long)(blk - blocksA - blocksB) * 256 + threadIdx.x) * 4;
    if (eg >= (long)nE + cE) return;
    int ss[4], pos[4], wh[4];
#pragma unroll
    for (int k = 0; k < 4; ++k) {
        long e = eg + k;
        if (e < nE) {
            ss[k] = ns[e]; int d = ndst[e];
            pos[k] = atomicAdd(&cur_n[d], 1); wh[k] = 0;
        } else if (e - nE < cE) {
            long ee = e - nE;
            ss[k] = cs[ee]; int d = cdst[ee];
            pos[k] = atomicAdd(&cur_c[d], 1); wh[k] = 1;
        } else wh[k] = -1;
    }
#pragma unroll
    for (int k = 0; k < 4; ++k) {
        if (wh[k] == 0)
            __builtin_nontemporal_store((unsigned short)(ss[k] + 1), csrc_n + pos[k]);
        else if (wh[k] == 1)
            __builtin_nontemporal_store((unsigned short)(ss[k] + 1), csrc_c + pos[k]);
    }
}

// ---------------- gather (CSR, rows padded to x8, m pre-scaled by di[src]) ---
// Slot value = s+1, 0 = pad. BN stats into 32-way replicated per-layer bins.
__global__ __launch_bounds__(256) void gather_dual(
    const unsigned short* __restrict__ m0, const int* __restrict__ rs0,
    const int* __restrict__ cnt0, const unsigned short* __restrict__ cs0,
    const float* __restrict__ di0, const float* __restrict__ b0,
    float* __restrict__ agg0, float* __restrict__ bins0, int n0, int blocksA,
    const unsigned short* __restrict__ m1, const int* __restrict__ rs1,
    const int* __restrict__ cnt1, const unsigned short* __restrict__ cs1,
    const float* __restrict__ di1, const float* __restrict__ b1,
    float* __restrict__ agg1, float* __restrict__ bins1, int n1) {
    __shared__ float lsum[4][128], lsq[4][128];
    int blk = blockIdx.x;
    const unsigned short* m; const int *rs, *cnt; const unsigned short* cs;
    const float *di, *bias;
    float *agg, *bins; int n, lb;
    if (blk < blocksA) { m = m0; rs = rs0; cnt = cnt0; cs = cs0; di = di0; bias = b0; agg = agg0; bins = bins0; n = n0; lb = blk; }
    else { m = m1; rs = rs1; cnt = cnt1; cs = cs1; di = di1; bias = b1; agg = agg1; bins = bins1; n = n1; lb = blk - blocksA; }
    int wib = threadIdx.x >> 6, lane = threadIdx.x & 63;
    int node = lb * 4 + wib;
    bool act = node < n;
    float a0 = 0.f, a1 = 0.f;
    if (act) {
        int start = rs[node];
        int end = start + ((cnt[node] + 7) & ~7);
        for (int i = start; i < end; i += 8) {
            int s[8]; unsigned int v[8];
#pragma unroll
            for (int j = 0; j < 8; ++j) s[j] = cs[i + j];
#pragma unroll
            for (int j = 0; j < 8; ++j) {
                int si = s[j] ? s[j] - 1 : node;
                v[j] = *(const unsigned int*)(m + (size_t)si * 128 + 2 * lane);
            }
#pragma unroll
            for (int j = 0; j < 8; ++j) {
                float wj = s[j] ? 1.f : 0.f;
                a0 += b2f((unsigned short)(v[j] & 0xffff)) * wj;
                a1 += b2f((unsigned short)(v[j] >> 16)) * wj;
            }
        }
        // self term (m already scaled by di[node]) then global di[node] scale
        unsigned int v = *(const unsigned int*)(m + (size_t)node * 128 + 2 * lane);
        a0 += b2f((unsigned short)(v & 0xffff));
        a1 += b2f((unsigned short)(v >> 16));
        float d = di[node];
        a0 = a0 * d + bias[2 * lane];
        a1 = a1 * d + bias[2 * lane + 1];
        float2 o; o.x = a0; o.y = a1;
        ((float2*)(agg + (size_t)node * 128))[lane] = o;
    }
    // ---- BN stats: block-level column reduce, then binned atomics ----
    lsum[wib][2 * lane] = a0;       lsum[wib][2 * lane + 1] = a1;
    lsq[wib][2 * lane] = a0 * a0;   lsq[wib][2 * lane + 1] = a1 * a1;
    __syncthreads();
    int t = threadIdx.x;
    int bb = (lb & 31) * 256;
    if (t < 128) {
        float v = lsum[0][t] + lsum[1][t] + lsum[2][t] + lsum[3][t];
        atomicAdd(&bins[bb + t], v);
    } else {
        int c = t - 128;
        float v = lsq[0][c] + lsq[1][c] + lsq[2][c] + lsq[3][c];
        atomicAdd(&bins[bb + 128 + c], v);
    }
}

// ---------------- fused BN-apply(i) + GEMM(i+1), dual-branch -----------------
__global__ __launch_bounds__(256) void applygemm_dual(
    const float* __restrict__ agg0, const float* __restrict__ bins0,
    const float* __restrict__ g0, const float* __restrict__ be0,
    unsigned short* __restrict__ hb0, const unsigned short* __restrict__ Bt0,
    const float* __restrict__ di0, unsigned short* __restrict__ D0,
    int n0, int blocksA, int useRes,
    const float* __restrict__ agg1, const float* __restrict__ bins1,
    const float* __restrict__ g1, const float* __restrict__ be1,
    unsigned short* __restrict__ hb1, const unsigned short* __restrict__ Bt1,
    const float* __restrict__ di1, unsigned short* __restrict__ D1, int n1) {
    __shared__ float sc[128], sh[128], bs[256];
    __shared__ unsigned short hrow_s[64 * 136];
    int blk = blockIdx.x;
    const float *agg, *bins, *g, *be, *di; unsigned short *hb, *D;
    const unsigned short* Bt; int n, lb;
    if (blk < blocksA) { agg = agg0; bins = bins0; g = g0; be = be0; hb = hb0; Bt = Bt0; di = di0; D = D0; n = n0; lb = blk; }
    else { agg = agg1; bins = bins1; g = g1; be = be1; hb = hb1; Bt = Bt1; di = di1; D = D1; n = n1; lb = blk - blocksA; }
    int t = threadIdx.x;
    {
        float a = 0.f;
#pragma unroll
        for (int b = 0; b < 32; ++b) a += bins[b * 256 + t];
        bs[t] = a;
    }
    __syncthreads();
    if (t < 128) {
        float inv = 1.f / (float)n;
        float mean = bs[t] * inv;
        float var = bs[128 + t] * inv - mean * mean;
        float rstd = rsqrtf(var + EPSV);
        float s = g[t] * rstd;
        sc[t] = s;
        sh[t] = be[t] - mean * s;
    }
    __syncthreads();
    int row0 = lb * 64;
#pragma unroll
    for (int it = 0; it < 8; ++it) {
        int base = row0 * 128 + it * 1024 + t * 4;
        if (base < n * 128) {
            float4 a = *(const float4*)(agg + base);
            ushort4 h = *(const ushort4*)(hb + base);
            int f = base & 127;
            float v0 = fmaxf(a.x * sc[f] + sh[f], 0.f);
            float v1 = fmaxf(a.y * sc[f + 1] + sh[f + 1], 0.f);
            float v2 = fmaxf(a.z * sc[f + 2] + sh[f + 2], 0.f);
            float v3 = fmaxf(a.w * sc[f + 3] + sh[f + 3], 0.f);
            if (useRes) { v0 += b2f(h.x); v1 += b2f(h.y); v2 += b2f(h.z); v3 += b2f(h.w); }
            ushort4 o; o.x = f2b(v0); o.y = f2b(v1); o.z = f2b(v2); o.w = f2b(v3);
            *(ushort4*)(hb + base) = o;
            int lr = (base >> 7) - row0;
            *(ushort4*)(hrow_s + lr * 136 + f) = o;
        }
    }
    __syncthreads();
    // ---- layer-(i+1) GEMM from LDS rows ----
    int lane = t & 63, w = t >> 6;
    int m0 = row0 + w * 16;
    if (m0 >= n) return;
    int r = lane & 15, q = lane >> 4;
    int arow = m0 + r; if (arow >= n) arow = n - 1;
    const unsigned short* ap = hrow_s + (arow - row0) * 136 + q * 8;
    bf16x8 afrag[4];
#pragma unroll
    for (int kc = 0; kc < 4; ++kc)
        afrag[kc] = *(const bf16x8*)(const void*)(ap + kc * 32);
    float dsc[4];
#pragma unroll
    for (int t4 = 0; t4 < 4; ++t4) {
        int row = m0 + q * 4 + t4; if (row >= n) row = n - 1;
        dsc[t4] = di[row];
    }
#pragma unroll
    for (int tt = 0; tt < 8; ++tt) {
        f32x4 acc = {0.f, 0.f, 0.f, 0.f};
#pragma unroll
        for (int kc = 0; kc < 4; ++kc) {
            bf16x8 bfrag = *(const bf16x8*)(const void*)(Bt + (((size_t)tt * 4 + kc) << 9) + lane * 8);
            acc = __builtin_amdgcn_mfma_f32_16x16x32_bf16(afrag[kc], bfrag, acc, 0, 0, 0);
        }
        int n0c = tt * 16;
#pragma unroll
        for (int t4 = 0; t4 < 4; ++t4) {
            int row = m0 + q * 4 + t4;
            if (row < n) D[(size_t)row * 128 + n0c + r] = f2b(acc[t4] * dsc[t4]);
        }
    }
}

// ---------------- BN finalize+apply (layer 2), dual-branch -------------------
// Comm blocks (32 rows each) additionally stage their bf16 rows in LDS and
// run the 24-tile QKV projection inline.
__global__ __launch_bounds__(256) void apply_dual(
    const float* __restrict__ agg0, const float* __restrict__ bins0,
    const float* __restrict__ g0, const float* __restrict__ be0,
    unsigned short* __restrict__ hb0, int n0, int blocksA, int useRes,
    const float* __restrict__ agg1, const float* __restrict__ bins1,
    const float* __restrict__ g1, const float* __restrict__ be1,
    unsigned short* __restrict__ hb1, int n1,
    int doCq, const unsigned short* __restrict__ WinB,
    const float* __restrict__ binb, float* __restrict__ cqkv) {
    __shared__ float sc[128], sh[128], bs[256];
    __shared__ unsigned short crow_s[32 * 136];
    int blk = blockIdx.x;
    bool isComm = blk >= blocksA;
    const float *agg, *bins, *g, *be; unsigned short* hb; int n, lb;
    if (!isComm) { agg = agg0; bins = bins0; g = g0; be = be0; hb = hb0; n = n0; lb = blk; }
    else { agg = agg1; bins = bins1; g = g1; be = be1; hb = hb1; n = n1; lb = blk - blocksA; }
    int t = threadIdx.x;
    {
        float a = 0.f;
#pragma unroll
        for (int b = 0; b < 32; ++b) a += bins[b * 256 + t];
        bs[t] = a;
    }
    __syncthreads();
    if (t < 128) {
        float inv = 1.f / (float)n;
        float mean = bs[t] * inv;
        float var = bs[128 + t] * inv - mean * mean;
        float rstd = rsqrtf(var + EPSV);
        float s = g[t] * rstd;
        sc[t] = s;
        sh[t] = be[t] - mean * s;
    }
    __syncthreads();
    bool stage = doCq && isComm;
#pragma unroll
    for (int it = 0; it < 4; ++it) {
        int base = (lb * 4 + it) * 1024 + t * 4;
        if (base < n * 128) {
            float4 a = *(const float4*)(agg + base);
            ushort4 h = *(const ushort4*)(hb + base);
            int f = base & 127;
            float v0 = fmaxf(a.x * sc[f] + sh[f], 0.f);
            float v1 = fmaxf(a.y * sc[f + 1] + sh[f + 1], 0.f);
            float v2 = fmaxf(a.z * sc[f + 2] + sh[f + 2], 0.f);
            float v3 = fmaxf(a.w * sc[f + 3] + sh[f + 3], 0.f);
            if (useRes) { v0 += b2f(h.x); v1 += b2f(h.y); v2 += b2f(h.z); v3 += b2f(h.w); }
            ushort4 o; o.x = f2b(v0); o.y = f2b(v1); o.z = f2b(v2); o.w = f2b(v3);
            *(ushort4*)(hb + base) = o;
            if (stage) {
                int row = (base >> 7) - lb * 32;
                *(ushort4*)(crow_s + row * 136 + (base & 127)) = o;
            }
        }
    }
    if (stage) {
        __syncthreads();
        int lane = t & 63, w = t >> 6;
        int r = lane & 15, q = lane >> 4;
        int rg = w & 1;
        const unsigned short* ap = crow_s + (rg * 16 + r) * 136 + q * 8;
        bf16x8 afrag[4];
#pragma unroll
        for (int kc = 0; kc < 4; ++kc)
            afrag[kc] = *(const bf16x8*)(const void*)(ap + kc * 32);
        int t0 = (w >> 1) * 12;
        for (int tt = t0; tt < t0 + 12; ++tt) {
            f32x4 acc = {0.f, 0.f, 0.f, 0.f};
#pragma unroll
            for (int kc = 0; kc < 4; ++kc) {
                bf16x8 bfrag = *(const bf16x8*)(const void*)(WinB + (((size_t)tt * 4 + kc) << 9) + lane * 8);
                acc = __builtin_amdgcn_mfma_f32_16x16x32_bf16(afrag[kc], bfrag, acc, 0, 0, 0);
            }
            int n0c = tt * 16;
            float bv = binb[n0c + r];
#pragma unroll
            for (int t4 = 0; t4 < 4; ++t4) {
                int row = lb * 32 + rg * 16 + q * 4 + t4;
                if (row < n) cqkv[(size_t)row * 384 + n0c + r] = acc[t4] + bv;
            }
        }
    }
}

// ---------------- fused MHA + mean + residual + LN + cls-W1 GEMM -------------
// obf_s stride = 136 shorts (272B): conflict-free b128 reads, 2-way writes.
__global__ __launch_bounds__(256) void mha_fused_kernel(
    const unsigned short* __restrict__ hbn, const int* __restrict__ map,
    const float* __restrict__ cqkv,
    const unsigned short* __restrict__ WinB, const float* __restrict__ bin,
    const unsigned short* __restrict__ WoutB, const float* __restrict__ bout,
    const float* __restrict__ lng, const float* __restrict__ lnb,
    const unsigned short* __restrict__ W1t, const float* __restrict__ b1v,
    float* __restrict__ z, float* __restrict__ zbins, int nN, int nC) {
    __shared__ unsigned short obf_s[16 * 136];   // phase B out; reused as hf_s in D/E
    __shared__ float att_s[16 * 132];

    int b = blockIdx.x;
    int hg = threadIdx.x >> 6;
    int lane = threadIdx.x & 63;
    int r = lane & 15, q = lane >> 4;

    // A-fragment: 16 contiguous node rows (coalesced)
    int arow = b * 16 + r; if (arow >= nN) arow = nN - 1;
    const unsigned short* ap = hbn + (size_t)arow * 128 + q * 8;
    bf16x8 afrag[4];
#pragma unroll
    for (int kc = 0; kc < 4; ++kc)
        afrag[kc] = *(const bf16x8*)(const void*)(ap + kc * 32);

    // comm-QKV base pointers for this lane's 4 output rows (q*4+t)
    const float* cp[4];
#pragma unroll
    for (int t = 0; t < 4; ++t) {
        int nt = b * 16 + q * 4 + t; if (nt >= nN) nt = nN - 1;
        int c = map[nt]; c = c < 0 ? 0 : (c >= nC ? nC - 1 : c);
        cp[t] = cqkv + (size_t)c * 384;
    }

#pragma unroll
    for (int c = 0; c < 2; ++c) {
        int h = hg * 2 + c;
        // ---- node q/k/v for head h over 16 nodes ----
        f32x4 qa, ka, va;
#pragma unroll
        for (int p = 0; p < 3; ++p) {
            int tt = p * 8 + h;
            f32x4 acc = {0.f, 0.f, 0.f, 0.f};
#pragma unroll
            for (int kc = 0; kc < 4; ++kc) {
                bf16x8 bfrag = *(const bf16x8*)(const void*)(WinB + (((size_t)tt * 4 + kc) << 9) + lane * 8);
                acc = __builtin_amdgcn_mfma_f32_16x16x32_bf16(afrag[kc], bfrag, acc, 0, 0, 0);
            }
            float bv = bin[tt * 16 + r];
#pragma unroll
            for (int t = 0; t < 4; ++t) acc[t] += bv;
            if (p == 0) qa = acc; else if (p == 1) ka = acc; else va = acc;
        }
        // ---- gather precomputed comm q/k/v (dim r of head h) ----
        float qc[4], kc_[4], vc[4];
#pragma unroll
        for (int t = 0; t < 4; ++t) {
            const float* cpt = cp[t] + h * 16 + r;
            qc[t] = cpt[0]; kc_[t] = cpt[128]; vc[t] = cpt[256];
        }
        // ---- 2x2 attention per node, mean over the two query rows ----
#pragma unroll
        for (int t = 0; t < 4; ++t) {
            float s00 = qa[t] * ka[t];     // q_node . k_node
            float s01 = qa[t] * kc_[t];    // q_node . k_comm
            float s10 = qc[t] * ka[t];     // q_comm . k_node
            float s11 = qc[t] * kc_[t];    // q_comm . k_comm
#pragma unroll
            for (int mku = 1; mku <= 8; mku <<= 1) {
                s00 += __shfl_xor(s00, mku); s01 += __shfl_xor(s01, mku);
                s10 += __shfl_xor(s10, mku); s11 += __shfl_xor(s11, mku);
            }
            s00 *= 0.25f; s01 *= 0.25f; s10 *= 0.25f; s11 *= 0.25f;
            float m0 = fmaxf(s00, s01), m1 = fmaxf(s10, s11);
            float e00 = __expf(s00 - m0), e01 = __expf(s01 - m0);
            float e10 = __expf(s10 - m1), e11 = __expf(s11 - m1);
            float i0 = 1.f / (e00 + e01), i1 = 1.f / (e10 + e11);
            float o0 = (e00 * va[t] + e01 * vc[t]) * i0;
            float o1 = (e10 * va[t] + e11 * vc[t]) * i1;
            obf_s[(q * 4 + t) * 136 + h * 16 + r] = f2b(0.5f * (o0 + o1));
        }
    }
    __syncthreads();

    // ---- out-proj on mean rows; wave hg handles tiles {2hg, 2hg+1} ----
    bf16x8 ofrag[4];
#pragma unroll
    for (int kc = 0; kc < 4; ++kc)
        ofrag[kc] = *(const bf16x8*)(const void*)(obf_s + r * 136 + q * 8 + kc * 32);
#pragma unroll
    for (int c = 0; c < 2; ++c) {
        int tt = hg * 2 + c;
        f32x4 acc = {0.f, 0.f, 0.f, 0.f};
#pragma unroll
        for (int kc = 0; kc < 4; ++kc) {
            bf16x8 bfrag = *(const bf16x8*)(const void*)(WoutB + (((size_t)tt * 4 + kc) << 9) + lane * 8);
            acc = __builtin_amdgcn_mfma_f32_16x16x32_bf16(ofrag[kc], bfrag, acc, 0, 0, 0);
        }
        int n0 = tt * 16;
        float bv = bout[n0 + r];
#pragma unroll
        for (int t = 0; t < 4; ++t)
            att_s[(q * 4 + t) * 132 + n0 + r] = acc[t] + bv;
    }
    __syncthreads();
    // NOTE: all ofrag reads of obf_s completed before the barrier above ->
    // obf_s is now reusable as hf_s (same stride 136).
    unsigned short* hf_s = obf_s;

    // ---- residual + LayerNorm (16 lanes per node, 8 cols each) -> LDS ----
    {
        int nl = threadIdx.x >> 4;     // 0..15: node within block
        int j = threadIdx.x & 15;      // 0..15: col group (8 cols)
        int gnode = b * 16 + nl;
        if (gnode >= nN) gnode = nN - 1;
        const unsigned short* hrow = hbn + (size_t)gnode * 128 + j * 8;
        ushort4 ha = *(const ushort4*)(hrow);
        ushort4 hbv = *(const ushort4*)(hrow + 4);
        float x[8]; float s = 0.f, s2 = 0.f;
        x[0] = att_s[nl * 132 + j * 8 + 0] + b2f(ha.x);
        x[1] = att_s[nl * 132 + j * 8 + 1] + b2f(ha.y);
        x[2] = att_s[nl * 132 + j * 8 + 2] + b2f(ha.z);
        x[3] = att_s[nl * 132 + j * 8 + 3] + b2f(ha.w);
        x[4] = att_s[nl * 132 + j * 8 + 4] + b2f(hbv.x);
        x[5] = att_s[nl * 132 + j * 8 + 5] + b2f(hbv.y);
        x[6] = att_s[nl * 132 + j * 8 + 6] + b2f(hbv.z);
        x[7] = att_s[nl * 132 + j * 8 + 7] + b2f(hbv.w);
#pragma unroll
        for (int i = 0; i < 8; ++i) { s += x[i]; s2 += x[i] * x[i]; }
        s += __shfl_xor(s, 1);  s2 += __shfl_xor(s2, 1);
        s += __shfl_xor(s, 2);  s2 += __shfl_xor(s2, 2);
        s += __shfl_xor(s, 4);  s2 += __shfl_xor(s2, 4);
        s += __shfl_xor(s, 8);  s2 += __shfl_xor(s2, 8);
        float mu = s * (1.f / 128.f);
        float var = s2 * (1.f / 128.f) - mu * mu;
        float rstd = rsqrtf(var + EPSV);
        ushort4 o1, o2;
        o1.x = f2b((x[0] - mu) * rstd * lng[j * 8 + 0] + lnb[j * 8 + 0]);
        o1.y = f2b((x[1] - mu) * rstd * lng[j * 8 + 1] + lnb[j * 8 + 1]);
        o1.z = f2b((x[2] - mu) * rstd * lng[j * 8 + 2] + lnb[j * 8 + 2]);
        o1.w = f2b((x[3] - mu) * rstd * lng[j * 8 + 3] + lnb[j * 8 + 3]);
        o2.x = f2b((x[4] - mu) * rstd * lng[j * 8 + 4] + lnb[j * 8 + 4]);
        o2.y = f2b((x[5] - mu) * rstd * lng[j * 8 + 5] + lnb[j * 8 + 5]);
        o2.z = f2b((x[6] - mu) * rstd * lng[j * 8 + 6] + lnb[j * 8 + 6]);
        o2.w = f2b((x[7] - mu) * rstd * lng[j * 8 + 7] + lnb[j * 8 + 7]);
        *(ushort4*)(hf_s + nl * 136 + j * 8) = o1;
        *(ushort4*)(hf_s + nl * 136 + j * 8 + 4) = o2;
    }
    __syncthreads();

    // ---- classifier W1 tile: wave hg -> cols [hg*16, hg*16+16) of z ----
    {
        bf16x8 hfrag[4];
#pragma unroll
        for (int kc = 0; kc < 4; ++kc)
            hfrag[kc] = *(const bf16x8*)(const void*)(hf_s + r * 136 + q * 8 + kc * 32);
        f32x4 acc = {0.f, 0.f, 0.f, 0.f};
#pragma unroll
        for (int kc = 0; kc < 4; ++kc) {
            bf16x8 bfrag = *(const bf16x8*)(const void*)(W1t + (((size_t)hg * 4 + kc) << 9) + lane * 8);
            acc = __builtin_amdgcn_mfma_f32_16x16x32_bf16(hfrag[kc], bfrag, acc, 0, 0, 0);
        }
        float bv = b1v[hg * 16 + r];
        float s = 0.f, s2 = 0.f;
#pragma unroll
        for (int t = 0; t < 4; ++t) {
            int row = b * 16 + q * 4 + t;
            if (row < nN) {
                float v = acc[t] + bv;
                z[(size_t)row * 64 + hg * 16 + r] = v;
                s += v; s2 += v * v;
            }
        }
        // reduce across q (lanes sharing col): q bits are lane bits 4,5
        s += __shfl_xor(s, 16);  s2 += __shfl_xor(s2, 16);
        s += __shfl_xor(s, 32);  s2 += __shfl_xor(s2, 32);
        if (lane < 16) {
            int bb = (b & 31) * 128;
            atomicAdd(&zbins[bb + hg * 16 + r], s);
            atomicAdd(&zbins[bb + 64 + hg * 16 + r], s2);
        }
    }
}

// ---------------- final: BN(inline zbins reduce)+ReLU+Linear(64,10)+lsm ------
__global__ __launch_bounds__(256) void final_kernel(const float* __restrict__ z,
                                                    const float* __restrict__ zbins,
                                                    const float* __restrict__ g,
                                                    const float* __restrict__ be,
                                                    const float* __restrict__ W2,
                                                    const float* __restrict__ b2v,
                                                    float* __restrict__ out, int nN) {
    __shared__ float zs[128];
    int t = threadIdx.x;
    if (t < 128) {
        float a = 0.f;
#pragma unroll
        for (int b = 0; b < 32; ++b) a += zbins[b * 128 + t];
        zs[t] = a;
    }
    __syncthreads();
    int lane = t & 63;
    float inv = 1.f / (float)nN;
    float mean = zs[lane] * inv;
    float var = zs[64 + lane] * inv - mean * mean;
    float sc = g[lane] * rsqrtf(var + EPSV);
    float sh = be[lane] - mean * sc;
    const float* wrow = W2 + lane * 10;
#pragma unroll
    for (int it = 0; it < 4; ++it) {
        int node = blockIdx.x * 16 + (t >> 6) * 4 + it;
        float v = 0.f;
        if (node < nN) v = fmaxf(z[(size_t)node * 64 + lane] * sc + sh, 0.f);
        float p[10];
#pragma unroll
        for (int c = 0; c < 10; ++c) p[c] = v * wrow[c];
#pragma unroll
        for (int off = 32; off >= 1; off >>= 1) {
#pragma unroll
            for (int c = 0; c < 10; ++c) p[c] += __shfl_xor(p[c], off);
        }
        if (node < nN) {
            float l[10], mx = -1e30f;
#pragma unroll
            for (int c = 0; c < 10; ++c) { l[c] = p[c] + b2v[c]; mx = fmaxf(mx, l[c]); }
            float se = 0.f;
#pragma unroll
            for (int c = 0; c < 10; ++c) se += expf(l[c] - mx);
            float lse = mx + logf(se);
            if (lane < 10) out[(size_t)node * 10 + lane] = l[lane] - lse;
        }
    }
}

// ---------------------------------------------------------------------------
static inline int cdiv(long a, long b) { return (int)((a + b - 1) / b); }

extern "C" void kernel_launch(void* const* d_in, const int* in_sizes, int n_in,
                              void* d_out, int out_size, void* d_ws, size_t ws_size,
                              hipStream_t stream) {
    const float* node_feat = (const float*)d_in[0];
    const int*   nedge     = (const int*)d_in[1];
    const float* comm_feat = (const float*)d_in[2];
    const int*   cedge     = (const int*)d_in[3];
    const int*   n2c       = (const int*)d_in[4];
    const float* node_W    = (const float*)d_in[5];
    const float* node_b    = (const float*)d_in[6];
    const float* node_g    = (const float*)d_in[7];
    const float* node_beta = (const float*)d_in[8];
    const float* comm_W    = (const float*)d_in[9];
    const float* comm_b    = (const float*)d_in[10];
    const float* comm_g    = (const float*)d_in[11];
    const float* comm_beta = (const float*)d_in[12];
    const float* attn_in_w = (const float*)d_in[13];
    const float* attn_in_b = (const float*)d_in[14];
    const float* attn_out_w= (const float*)d_in[15];
    const float* attn_out_b= (const float*)d_in[16];
    const float* ln_g      = (const float*)d_in[17];
    const float* ln_b      = (const float*)d_in[18];
    const float* cls_W1    = (const float*)d_in[19];
    const float* cls_b1    = (const float*)d_in[20];
    const float* cls_bn_g  = (const float*)d_in[21];
    const float* cls_bn_b  = (const float*)d_in[22];
    const float* cls_W2    = (const float*)d_in[23];
    const float* cls_b2    = (const float*)d_in[24];

    const int nN = in_sizes[0] / 128;
    const int nE = in_sizes[1] / 2;
    const int nC = in_sizes[2] / 128;
    const int cE = in_sizes[3] / 2;
    const int padE_n = nE + 8 * nN;
    const int padE_c = cE + 8 * nC;

    char* ws = (char*)d_ws;
    size_t off = 0;
    auto alloc = [&](size_t bytes) -> char* {
        char* p = ws + off;
        off = (off + bytes + 255) & ~(size_t)255;
        return p;
    };
    // ---- contiguous zero region (single memset; includes csrc: 0 = pad) ----
    size_t zero_begin = off;
    int*   cnt_n  = (int*)alloc((size_t)nN * 4);
    int*   cur_n  = (int*)alloc((size_t)nN * 4);
    int*   cnt_c  = (int*)alloc((size_t)nC * 4);
    int*   cur_c  = (int*)alloc((size_t)nC * 4);
    float* bins_n = (float*)alloc((size_t)3 * 32 * 256 * 4);  // per-layer
    float* bins_c = (float*)alloc((size_t)3 * 32 * 256 * 4);  // per-layer
    float* zbins  = (float*)alloc((size_t)32 * 128 * 4);
    unsigned short* csrc_n = (unsigned short*)alloc((size_t)padE_n * 2);
    unsigned short* csrc_c = (unsigned short*)alloc((size_t)padE_c * 2);
    size_t zero_bytes = off - zero_begin;
    // ---- CSR aux ----
    int*   rs_n   = (int*)alloc((size_t)(nN + 1) * 4);
    int*   bsum_n = (int*)alloc(256 * 4);
    float* dinv_n = (float*)alloc((size_t)nN * 4);
    int*   rs_c   = (int*)alloc((size_t)(nC + 1) * 4);
    int*   bsum_c = (int*)alloc(256 * 4);
    float* dinv_c = (float*)alloc((size_t)nC * 4);
    // ---- activations / weights ----
    unsigned short* hb_n  = (unsigned short*)alloc((size_t)nN * 256);
    unsigned short* hb_c  = (unsigned short*)alloc((size_t)nC * 256);
    unsigned short* cfb   = (unsigned short*)alloc((size_t)nC * 256);
    unsigned short* m_cb  = (unsigned short*)alloc((size_t)nC * 256);
    float*          agg_c = (float*)alloc((size_t)nC * 512);
    float*          cqkv  = (float*)alloc((size_t)nC * 384 * 4);
    unsigned short* WtN  = (unsigned short*)alloc((size_t)3 * 16384 * 2);
    unsigned short* WtC  = (unsigned short*)alloc((size_t)3 * 16384 * 2);
    unsigned short* W1t  = (unsigned short*)alloc((size_t)64 * 128 * 2);
    unsigned short* WinB = (unsigned short*)alloc((size_t)384 * 128 * 2);
    unsigned short* WoutB= (unsigned short*)alloc((size_t)128 * 128 * 2);
    unsigned short* m_nb = (unsigned short*)alloc((size_t)nN * 256);
    float*          agg_n= (float*)alloc((size_t)nN * 512);
    // aliases (disjoint liveness)
    unsigned short* nfb  = (unsigned short*)agg_n;
    float*          z    = agg_n;   // free after layer-3 apply

    hipMemsetAsync(ws + zero_begin, 0, zero_bytes, stream);

    // ---- prep (+ edge-degree count, 4 edges/thread, as trailing blocks) ----
    long prepN = 49152L * 3 + 8192 + 16384 + (long)nC * 128 + (long)nN * 128;
    long cntThreads = ((long)nE + cE + 3) / 4;
    long prepTotal = prepN + cntThreads;
    prep_kernel<<<cdiv(prepTotal, 256), 256, 0, stream>>>(
        node_W, comm_W, cls_W1, attn_in_w, attn_out_w, comm_feat, node_feat,
        WtN, WtC, W1t, WinB, WoutB, cfb, nfb, nC * 128, nN * 128,
        nedge + nE, cnt_n, nE, cedge + cE, cnt_c, cE);

    // ---- CSR scan (rows padded to x8) ----
    int nbN = cdiv(nN, 1024), nbC = cdiv(nC, 1024);
    int dinvB = cdiv((long)nN + nC, 1024);
    scan_block_dual<<<nbN + nbC + dinvB, 1024, 0, stream>>>(
        cnt_n, rs_n, bsum_n, nN, nbN, cnt_c, rs_c, bsum_c, nC, dinv_n, dinv_c);
    scan_add_dual<<<cdiv((long)nN + nC, 256), 256, 0, stream>>>(
        rs_n, bsum_n, cur_n, nN, rs_c, bsum_c, cur_c, nC);

    // ---- GCN layers ----
    int gemmA = cdiv(nN, 64), gemmB = cdiv(nC, 64);
    int fillB = cdiv((long)nE + cE, 1024);   // 4 edges/thread
    int gatA = cdiv(nN, 4), gatB = cdiv(nC, 4);
    int appA = cdiv((long)nN * 128, 4096), appB = cdiv((long)nC * 128, 4096);

    // L0 gemm + CSR fill (independent work, one dispatch)
    gemm_fill_kernel<<<gemmA + gemmB + fillB, 256, 0, stream>>>(
        nfb, WtN, dinv_n, m_nb, nN, gemmA,
        cfb, WtC, dinv_c, m_cb, nC, gemmB,
        nedge, nedge + nE, cur_n, csrc_n, nE,
        cedge, cedge + cE, cur_c, csrc_c, cE);
    // gather L0
    gather_dual<<<gatA + gatB, 256, 0, stream>>>(
        m_nb, rs_n, cnt_n, csrc_n, dinv_n, node_b, agg_n, bins_n, nN, gatA,
        m_cb, rs_c, cnt_c, csrc_c, dinv_c, comm_b, agg_c, bins_c, nC);
    // apply L0 + gemm L1 (fused)
    applygemm_dual<<<gemmA + gemmB, 256, 0, stream>>>(
        agg_n, bins_n, node_g, node_beta, hb_n, WtN + 16384, dinv_n, m_nb, nN, gemmA, 0,
        agg_c, bins_c, comm_g, comm_beta, hb_c, WtC + 16384, dinv_c, m_cb, nC);
    // gather L1
    gather_dual<<<gatA + gatB, 256, 0, stream>>>(
        m_nb, rs_n, cnt_n, csrc_n, dinv_n, node_b + 128, agg_n, bins_n + 32 * 256, nN, gatA,
        m_cb, rs_c, cnt_c, csrc_c, dinv_c, comm_b + 128, agg_c, bins_c + 32 * 256, nC);
    // apply L1 + gemm L2 (fused)
    applygemm_dual<<<gemmA + gemmB, 256, 0, stream>>>(
        agg_n, bins_n + 32 * 256, node_g + 128, node_beta + 128, hb_n, WtN + 2 * 16384, dinv_n, m_nb, nN, gemmA, 1,
        agg_c, bins_c + 32 * 256, comm_g + 128, comm_beta + 128, hb_c, WtC + 2 * 16384, dinv_c, m_cb, nC);
    // gather L2
    gather_dual<<<gatA + gatB, 256, 0, stream>>>(
        m_nb, rs_n, cnt_n, csrc_n, dinv_n, node_b + 256, agg_n, bins_n + 2 * 32 * 256, nN, gatA,
        m_cb, rs_c, cnt_c, csrc_c, dinv_c, comm_b + 256, agg_c, bins_c + 2 * 32 * 256, nC);
    // apply L2 (+ inline comm QKV projection)
    apply_dual<<<appA + appB, 256, 0, stream>>>(
        agg_n, bins_n + 2 * 32 * 256, node_g + 256, node_beta + 256, hb_n, nN, appA, 1,
        agg_c, bins_c + 2 * 32 * 256, comm_g + 256, comm_beta + 256, hb_c, nC,
        1, WinB, attn_in_b, cqkv);

    // ---- fused MHA + mean + residual + LN + cls-W1 (16 nodes/block) ----
    mha_fused_kernel<<<cdiv(nN, 16), 256, 0, stream>>>(
        hb_n, n2c, cqkv, WinB, attn_in_b, WoutB, attn_out_b, ln_g, ln_b,
        W1t, cls_b1, z, zbins, nN, nC);

    // ---- classifier tail (zbins reduced inline per block) ----
    final_kernel<<<cdiv(nN, 16), 256, 0, stream>>>(
        z, zbins, cls_bn_g, cls_bn_b, cls_W2, cls_b2, (float*)d_out, nN);
}

// Round 14
// 441.313 us; speedup vs baseline: 1.0106x; 1.0106x over previous
//
#include <hip/hip_runtime.h>
#include <hip/hip_bf16.h>
#include <cstdint>
#include <cstddef>

// ---------------------------------------------------------------------------
// ImprovedCrossScaleGNN on MI355X (gfx950).
// Inputs float32 + int32, output float32. bf16 MFMA GEMMs, f32 stats.
// R24->R25: node-side BN-apply of layer 2 FUSED into mha (block-local: mha
// block b owns rows [16b,16b+16); scale from L2-hot bins reduce; residual =
// layer-1 hb_n). hb_n post-L2 never touches global (-12.8MB write, -25.6MB
// mha re-read; reads agg_n+old hb_n coalesced instead). apply_dual now runs
// comm blocks only (cqkv producer, must precede mha). Same op order ->
// bit-identical. R24 note: 400K LDS conflicts were NOT obf_s (unchanged by
// stride fix) and not on the critical path.
// ---------------------------------------------------------------------------

typedef __attribute__((ext_vector_type(8))) short bf16x8;
typedef __attribute__((ext_vector_type(4))) float f32x4;

#define EPSV 1e-5f

__device__ __forceinline__ float b2f(unsigned short u) {
    union { unsigned int i; float f; } x; x.i = ((unsigned int)u) << 16; return x.f;
}
__device__ __forceinline__ unsigned short f2b(float f) {
    union { float f; unsigned int i; } x; x.f = f;
    unsigned int i = x.i;
    return (unsigned short)((i + 0x7fffu + ((i >> 16) & 1u)) >> 16);
}

// ---------------- prep: weights -> fragment-linear bf16 + feature casts ------
// Trailing range: edge-degree count, 4 contiguous edges per thread (ILP).
__global__ void prep_kernel(const float* __restrict__ node_W, const float* __restrict__ comm_W,
                            const float* __restrict__ cls_W1, const float* __restrict__ attn_in_w,
                            const float* __restrict__ attn_out_w, const float* __restrict__ comm_feat,
                            const float* __restrict__ node_feat,
                            unsigned short* __restrict__ WtN, unsigned short* __restrict__ WtC,
                            unsigned short* __restrict__ W1t, unsigned short* __restrict__ WinB,
                            unsigned short* __restrict__ WoutB, unsigned short* __restrict__ cfb,
                            unsigned short* __restrict__ nfb, int nC128, int nN128,
                            const int* __restrict__ ndst, int* __restrict__ cnt_n, int nE,
                            const int* __restrict__ cdst, int* __restrict__ cnt_c, int cE) {
    int idx = blockIdx.x * 256 + threadIdx.x;
    if (idx < 49152) {  // node_W [3][128][128] (W[k][col])
        int l = idx >> 14, e = idx & 16383;
        int j = e & 7, lane = (e >> 3) & 63, kc = (e >> 9) & 3, t = e >> 11;
        int col = t * 16 + (lane & 15);
        int k = (lane >> 4) * 8 + kc * 32 + j;
        WtN[idx] = f2b(node_W[l * 16384 + k * 128 + col]); return;
    }
    idx -= 49152;
    if (idx < 49152) {  // comm_W
        int l = idx >> 14, e = idx & 16383;
        int j = e & 7, lane = (e >> 3) & 63, kc = (e >> 9) & 3, t = e >> 11;
        int col = t * 16 + (lane & 15);
        int k = (lane >> 4) * 8 + kc * 32 + j;
        WtC[idx] = f2b(comm_W[l * 16384 + k * 128 + col]); return;
    }
    idx -= 49152;
    if (idx < 8192) {   // cls_W1 [128][64] (W[k][col]), 4 tiles
        int e = idx;
        int j = e & 7, lane = (e >> 3) & 63, kc = (e >> 9) & 3, t = e >> 11;
        int col = t * 16 + (lane & 15);
        int k = (lane >> 4) * 8 + kc * 32 + j;
        W1t[idx] = f2b(cls_W1[k * 64 + col]); return;
    }
    idx -= 8192;
    if (idx < 49152) {  // attn_in_w [384][128] = Bt[col][k], 24 tiles
        int e = idx;
        int j = e & 7, lane = (e >> 3) & 63, kc = (e >> 9) & 3, t = e >> 11;
        int col = t * 16 + (lane & 15);
        int k = (lane >> 4) * 8 + kc * 32 + j;
        WinB[idx] = f2b(attn_in_w[col * 128 + k]); return;
    }
    idx -= 49152;
    if (idx < 16384) {  // attn_out_w [128][128] = Bt[col][k], 8 tiles
        int e = idx;
        int j = e & 7, lane = (e >> 3) & 63, kc = (e >> 9) & 3, t = e >> 11;
        int col = t * 16 + (lane & 15);
        int k = (lane >> 4) * 8 + kc * 32 + j;
        WoutB[idx] = f2b(attn_out_w[col * 128 + k]); return;
    }
    idx -= 16384;
    if (idx < nC128) { cfb[idx] = f2b(comm_feat[idx]); return; }
    idx -= nC128;
    if (idx < nN128) { nfb[idx] = f2b(node_feat[idx]); return; }
    idx -= nN128;
    // count region: 4 contiguous edges per thread (independent atomics)
    long eg = (long)idx * 4;
    if (eg < (long)nE + cE) {
        int dd[4]; int wh[4];
#pragma unroll
        for (int k = 0; k < 4; ++k) {
            long e = eg + k;
            if (e < nE) { dd[k] = ndst[e]; wh[k] = 0; }
            else if (e - nE < cE) { dd[k] = cdst[e - nE]; wh[k] = 1; }
            else wh[k] = -1;
        }
#pragma unroll
        for (int k = 0; k < 4; ++k) {
            if (wh[k] == 0) atomicAdd(&cnt_n[dd[k]], 1);
            else if (wh[k] == 1) atomicAdd(&cnt_c[dd[k]], 1);
        }
    }
}

// scans PADDED counts: ceil8(cnt). Extra trailing blocks compute dinv.
__global__ void scan_block_dual(const int* __restrict__ cnt_n, int* __restrict__ rs_n,
                                int* __restrict__ bsum_n, int nN, int nbN,
                                const int* __restrict__ cnt_c, int* __restrict__ rs_c,
                                int* __restrict__ bsum_c, int nC,
                                float* __restrict__ di_n, float* __restrict__ di_c) {
    __shared__ int tmp[2048];
    int nbC = (nC + 1023) >> 10;
    int extra = (int)blockIdx.x - (nbN + nbC);
    if (extra >= 0) {  // dinv region
        int g = extra * 1024 + (int)threadIdx.x;
        if (g < nN) di_n[g] = rsqrtf((float)cnt_n[g] + 1.0f);
        else { int gc = g - nN; if (gc < nC) di_c[gc] = rsqrtf((float)cnt_c[gc] + 1.0f); }
        return;
    }
    const int* cnt; int* excl; int* bsum; int n, lb;
    if ((int)blockIdx.x < nbN) { cnt = cnt_n; excl = rs_n; bsum = bsum_n; n = nN; lb = blockIdx.x; }
    else { cnt = cnt_c; excl = rs_c; bsum = bsum_c; n = nC; lb = blockIdx.x - nbN; }
    int tid = threadIdx.x;
    int gid = lb * 1024 + tid;
    int v = (gid < n) ? ((cnt[gid] + 7) & ~7) : 0;
    int buf = 0;
    tmp[tid] = v;
    __syncthreads();
    for (int d = 1; d < 1024; d <<= 1) {
        int t = tmp[buf * 1024 + tid];
        int add = (tid >= d) ? tmp[buf * 1024 + tid - d] : 0;
        tmp[(1 - buf) * 1024 + tid] = t + add;
        buf = 1 - buf;
        __syncthreads();
    }
    int inc = tmp[buf * 1024 + tid];
    if (gid < n) excl[gid] = inc - v;
    if (tid == 1023) bsum[lb] = inc;
}

// finalize rs from RAW bsum (inline prefix) AND preload cur = rs.
__global__ void scan_add_dual(int* __restrict__ rs_n, const int* __restrict__ bsum_n,
                              int* __restrict__ cur_n, int nN,
                              int* __restrict__ rs_c, const int* __restrict__ bsum_c,
                              int* __restrict__ cur_c, int nC) {
    int gid = blockIdx.x * 256 + threadIdx.x;
    if (gid < nN) {
        int lb = gid >> 10;
        int p = 0;
        for (int i = 0; i < lb; ++i) p += bsum_n[i];
        int v = rs_n[gid] + p;
        rs_n[gid] = v; cur_n[gid] = v;
    } else {
        int g = gid - nN;
        if (g < nC) {
            int lb = g >> 10;
            int p = 0;
            for (int i = 0; i < lb; ++i) p += bsum_c[i];
            int v = rs_c[g] + p;
            rs_c[g] = v; cur_c[g] = v;
        }
    }
}

// ---------------- MFMA GEMM wave body: 16 rows x 128 cols, bf16 out ----------
__device__ __forceinline__ void gemm_wave_128(const unsigned short* __restrict__ A,
                                              const unsigned short* __restrict__ Bt,
                                              const float* __restrict__ di,
                                              unsigned short* __restrict__ D,
                                              int M, int m0, int lane) {
    int r = lane & 15, q = lane >> 4;
    int arow = m0 + r; if (arow >= M) arow = M - 1;
    const unsigned short* ap = A + (size_t)arow * 128 + q * 8;
    bf16x8 afrag[4];
#pragma unroll
    for (int kc = 0; kc < 4; ++kc)
        afrag[kc] = *(const bf16x8*)(const void*)(ap + kc * 32);
    float dsc[4];
#pragma unroll
    for (int t = 0; t < 4; ++t) {
        int row = m0 + q * 4 + t; if (row >= M) row = M - 1;
        dsc[t] = di[row];
    }
#pragma unroll
    for (int tt = 0; tt < 8; ++tt) {
        f32x4 acc = {0.f, 0.f, 0.f, 0.f};
#pragma unroll
        for (int kc = 0; kc < 4; ++kc) {
            bf16x8 bfrag = *(const bf16x8*)(const void*)(Bt + (((size_t)tt * 4 + kc) << 9) + lane * 8);
            acc = __builtin_amdgcn_mfma_f32_16x16x32_bf16(afrag[kc], bfrag, acc, 0, 0, 0);
        }
        int n0 = tt * 16;
#pragma unroll
        for (int t = 0; t < 4; ++t) {
            int row = m0 + q * 4 + t;
            if (row < M) D[(size_t)row * 128 + n0 + r] = f2b(acc[t] * dsc[t]);
        }
    }
}

// layer-0 gemm + CSR fill merged. Fill: 4 contiguous edges per thread;
// phase 1 issues 4 independent atomicAdds, phase 2 the 4 nt-stores of s+1.
__global__ __launch_bounds__(256) void gemm_fill_kernel(
    const unsigned short* __restrict__ A0, const unsigned short* __restrict__ Bt0,
    const float* __restrict__ di0, unsigned short* __restrict__ D0, int M0, int blocksA,
    const unsigned short* __restrict__ A1, const unsigned short* __restrict__ Bt1,
    const float* __restrict__ di1, unsigned short* __restrict__ D1, int M1, int blocksB,
    const int* __restrict__ ns, const int* __restrict__ ndst,
    int* __restrict__ cur_n, unsigned short* __restrict__ csrc_n, int nE,
    const int* __restrict__ cs, const int* __restrict__ cdst,
    int* __restrict__ cur_c, unsigned short* __restrict__ csrc_c, int cE) {
    int blk = blockIdx.x;
    if (blk < blocksA + blocksB) {
        const unsigned short *A, *Bt; const float* di; unsigned short* D; int M, lb;
        if (blk < blocksA) { A = A0; Bt = Bt0; di = di0; D = D0; M = M0; lb = blk; }
        else { A = A1; Bt = Bt1; di = di1; D = D1; M = M1; lb = blk - blocksA; }
        int m0 = (lb * 4 + (int)(threadIdx.x >> 6)) * 16;
        if (m0 >= M) return;
        gemm_wave_128(A, Bt, di, D, M, m0, threadIdx.x & 63);
        return;
    }
    long eg = ((long)(blk - blocksA - blocksB) * 256 + threadIdx.x) * 4;
    if (eg >= (long)nE + cE) return;
    int ss[4], pos[4], wh[4];
#pragma unroll
    for (int k = 0; k < 4; ++k) {
        long e = eg + k;
        if (e < nE) {
            ss[k] = ns[e]; int d = ndst[e];
            pos[k] = atomicAdd(&cur_n[d], 1); wh[k] = 0;
        } else if (e - nE < cE) {
            long ee = e - nE;
            ss[k] = cs[ee]; int d = cdst[ee];
            pos[k] = atomicAdd(&cur_c[d], 1); wh[k] = 1;
        } else wh[k] = -1;
    }
#pragma unroll
    for (int k = 0; k < 4; ++k) {
        if (wh[k] == 0)
            __builtin_nontemporal_store((unsigned short)(ss[k] + 1), csrc_n + pos[k]);
        else if (wh[k] == 1)
            __builtin_nontemporal_store((unsigned short)(ss[k] + 1), csrc_c + pos[k]);
    }
}

// ---------------- gather (CSR, rows padded to x8, m pre-scaled by di[src]) ---
__global__ __launch_bounds__(256) void gather_dual(
    const unsigned short* __restrict__ m0, const int* __restrict__ rs0,
    const int* __restrict__ cnt0, const unsigned short* __restrict__ cs0,
    const float* __restrict__ di0, const float* __restrict__ b0,
    float* __restrict__ agg0, float* __restrict__ bins0, int n0, int blocksA,
    const unsigned short* __restrict__ m1, const int* __restrict__ rs1,
    const int* __restrict__ cnt1, const unsigned short* __restrict__ cs1,
    const float* __restrict__ di1, const float* __restrict__ b1,
    float* __restrict__ agg1, float* __restrict__ bins1, int n1) {
    __shared__ float lsum[4][128], lsq[4][128];
    int blk = blockIdx.x;
    const unsigned short* m; const int *rs, *cnt; const unsigned short* cs;
    const float *di, *bias;
    float *agg, *bins; int n, lb;
    if (blk < blocksA) { m = m0; rs = rs0; cnt = cnt0; cs = cs0; di = di0; bias = b0; agg = agg0; bins = bins0; n = n0; lb = blk; }
    else { m = m1; rs = rs1; cnt = cnt1; cs = cs1; di = di1; bias = b1; agg = agg1; bins = bins1; n = n1; lb = blk - blocksA; }
    int wib = threadIdx.x >> 6, lane = threadIdx.x & 63;
    int node = lb * 4 + wib;
    bool act = node < n;
    float a0 = 0.f, a1 = 0.f;
    if (act) {
        int start = rs[node];
        int end = start + ((cnt[node] + 7) & ~7);
        for (int i = start; i < end; i += 8) {
            int s[8]; unsigned int v[8];
#pragma unroll
            for (int j = 0; j < 8; ++j) s[j] = cs[i + j];
#pragma unroll
            for (int j = 0; j < 8; ++j) {
                int si = s[j] ? s[j] - 1 : node;
                v[j] = *(const unsigned int*)(m + (size_t)si * 128 + 2 * lane);
            }
#pragma unroll
            for (int j = 0; j < 8; ++j) {
                float wj = s[j] ? 1.f : 0.f;
                a0 += b2f((unsigned short)(v[j] & 0xffff)) * wj;
                a1 += b2f((unsigned short)(v[j] >> 16)) * wj;
            }
        }
        unsigned int v = *(const unsigned int*)(m + (size_t)node * 128 + 2 * lane);
        a0 += b2f((unsigned short)(v & 0xffff));
        a1 += b2f((unsigned short)(v >> 16));
        float d = di[node];
        a0 = a0 * d + bias[2 * lane];
        a1 = a1 * d + bias[2 * lane + 1];
        float2 o; o.x = a0; o.y = a1;
        ((float2*)(agg + (size_t)node * 128))[lane] = o;
    }
    lsum[wib][2 * lane] = a0;       lsum[wib][2 * lane + 1] = a1;
    lsq[wib][2 * lane] = a0 * a0;   lsq[wib][2 * lane + 1] = a1 * a1;
    __syncthreads();
    int t = threadIdx.x;
    int bb = (lb & 31) * 256;
    if (t < 128) {
        float v = lsum[0][t] + lsum[1][t] + lsum[2][t] + lsum[3][t];
        atomicAdd(&bins[bb + t], v);
    } else {
        int c = t - 128;
        float v = lsq[0][c] + lsq[1][c] + lsq[2][c] + lsq[3][c];
        atomicAdd(&bins[bb + 128 + c], v);
    }
}

// ---------------- fused BN-apply(i) + GEMM(i+1), dual-branch -----------------
__global__ __launch_bounds__(256) void applygemm_dual(
    const float* __restrict__ agg0, const float* __restrict__ bins0,
    const float* __restrict__ g0, const float* __restrict__ be0,
    unsigned short* __restrict__ hb0, const unsigned short* __restrict__ Bt0,
    const float* __restrict__ di0, unsigned short* __restrict__ D0,
    int n0, int blocksA, int useRes,
    const float* __restrict__ agg1, const float* __restrict__ bins1,
    const float* __restrict__ g1, const float* __restrict__ be1,
    unsigned short* __restrict__ hb1, const unsigned short* __restrict__ Bt1,
    const float* __restrict__ di1, unsigned short* __restrict__ D1, int n1) {
    __shared__ float sc[128], sh[128], bs[256];
    __shared__ unsigned short hrow_s[64 * 136];
    int blk = blockIdx.x;
    const float *agg, *bins, *g, *be, *di; unsigned short *hb, *D;
    const unsigned short* Bt; int n, lb;
    if (blk < blocksA) { agg = agg0; bins = bins0; g = g0; be = be0; hb = hb0; Bt = Bt0; di = di0; D = D0; n = n0; lb = blk; }
    else { agg = agg1; bins = bins1; g = g1; be = be1; hb = hb1; Bt = Bt1; di = di1; D = D1; n = n1; lb = blk - blocksA; }
    int t = threadIdx.x;
    {
        float a = 0.f;
#pragma unroll
        for (int b = 0; b < 32; ++b) a += bins[b * 256 + t];
        bs[t] = a;
    }
    __syncthreads();
    if (t < 128) {
        float inv = 1.f / (float)n;
        float mean = bs[t] * inv;
        float var = bs[128 + t] * inv - mean * mean;
        float rstd = rsqrtf(var + EPSV);
        float s = g[t] * rstd;
        sc[t] = s;
        sh[t] = be[t] - mean * s;
    }
    __syncthreads();
    int row0 = lb * 64;
#pragma unroll
    for (int it = 0; it < 8; ++it) {
        int base = row0 * 128 + it * 1024 + t * 4;
        if (base < n * 128) {
            float4 a = *(const float4*)(agg + base);
            ushort4 h = *(const ushort4*)(hb + base);
            int f = base & 127;
            float v0 = fmaxf(a.x * sc[f] + sh[f], 0.f);
            float v1 = fmaxf(a.y * sc[f + 1] + sh[f + 1], 0.f);
            float v2 = fmaxf(a.z * sc[f + 2] + sh[f + 2], 0.f);
            float v3 = fmaxf(a.w * sc[f + 3] + sh[f + 3], 0.f);
            if (useRes) { v0 += b2f(h.x); v1 += b2f(h.y); v2 += b2f(h.z); v3 += b2f(h.w); }
            ushort4 o; o.x = f2b(v0); o.y = f2b(v1); o.z = f2b(v2); o.w = f2b(v3);
            *(ushort4*)(hb + base) = o;
            int lr = (base >> 7) - row0;
            *(ushort4*)(hrow_s + lr * 136 + f) = o;
        }
    }
    __syncthreads();
    int lane = t & 63, w = t >> 6;
    int m0 = row0 + w * 16;
    if (m0 >= n) return;
    int r = lane & 15, q = lane >> 4;
    int arow = m0 + r; if (arow >= n) arow = n - 1;
    const unsigned short* ap = hrow_s + (arow - row0) * 136 + q * 8;
    bf16x8 afrag[4];
#pragma unroll
    for (int kc = 0; kc < 4; ++kc)
        afrag[kc] = *(const bf16x8*)(const void*)(ap + kc * 32);
    float dsc[4];
#pragma unroll
    for (int t4 = 0; t4 < 4; ++t4) {
        int row = m0 + q * 4 + t4; if (row >= n) row = n - 1;
        dsc[t4] = di[row];
    }
#pragma unroll
    for (int tt = 0; tt < 8; ++tt) {
        f32x4 acc = {0.f, 0.f, 0.f, 0.f};
#pragma unroll
        for (int kc = 0; kc < 4; ++kc) {
            bf16x8 bfrag = *(const bf16x8*)(const void*)(Bt + (((size_t)tt * 4 + kc) << 9) + lane * 8);
            acc = __builtin_amdgcn_mfma_f32_16x16x32_bf16(afrag[kc], bfrag, acc, 0, 0, 0);
        }
        int n0c = tt * 16;
#pragma unroll
        for (int t4 = 0; t4 < 4; ++t4) {
            int row = m0 + q * 4 + t4;
            if (row < n) D[(size_t)row * 128 + n0c + r] = f2b(acc[t4] * dsc[t4]);
        }
    }
}

// ---------------- BN finalize+apply (layer 2), COMM-ONLY now -----------------
// Blocks (32 rows each) apply BN+ReLU+res to hb_c, stage rows in LDS, run
// the 24-tile QKV projection inline -> cqkv.
__global__ __launch_bounds__(256) void apply_dual(
    const float* __restrict__ agg0, const float* __restrict__ bins0,
    const float* __restrict__ g0, const float* __restrict__ be0,
    unsigned short* __restrict__ hb0, int n0, int blocksA, int useRes,
    const float* __restrict__ agg1, const float* __restrict__ bins1,
    const float* __restrict__ g1, const float* __restrict__ be1,
    unsigned short* __restrict__ hb1, int n1,
    int doCq, const unsigned short* __restrict__ WinB,
    const float* __restrict__ binb, float* __restrict__ cqkv) {
    __shared__ float sc[128], sh[128], bs[256];
    __shared__ unsigned short crow_s[32 * 136];
    int blk = blockIdx.x;
    bool isComm = blk >= blocksA;
    const float *agg, *bins, *g, *be; unsigned short* hb; int n, lb;
    if (!isComm) { agg = agg0; bins = bins0; g = g0; be = be0; hb = hb0; n = n0; lb = blk; }
    else { agg = agg1; bins = bins1; g = g1; be = be1; hb = hb1; n = n1; lb = blk - blocksA; }
    int t = threadIdx.x;
    {
        float a = 0.f;
#pragma unroll
        for (int b = 0; b < 32; ++b) a += bins[b * 256 + t];
        bs[t] = a;
    }
    __syncthreads();
    if (t < 128) {
        float inv = 1.f / (float)n;
        float mean = bs[t] * inv;
        float var = bs[128 + t] * inv - mean * mean;
        float rstd = rsqrtf(var + EPSV);
        float s = g[t] * rstd;
        sc[t] = s;
        sh[t] = be[t] - mean * s;
    }
    __syncthreads();
    bool stage = doCq && isComm;
#pragma unroll
    for (int it = 0; it < 4; ++it) {
        int base = (lb * 4 + it) * 1024 + t * 4;
        if (base < n * 128) {
            float4 a = *(const float4*)(agg + base);
            ushort4 h = *(const ushort4*)(hb + base);
            int f = base & 127;
            float v0 = fmaxf(a.x * sc[f] + sh[f], 0.f);
            float v1 = fmaxf(a.y * sc[f + 1] + sh[f + 1], 0.f);
            float v2 = fmaxf(a.z * sc[f + 2] + sh[f + 2], 0.f);
            float v3 = fmaxf(a.w * sc[f + 3] + sh[f + 3], 0.f);
            if (useRes) { v0 += b2f(h.x); v1 += b2f(h.y); v2 += b2f(h.z); v3 += b2f(h.w); }
            ushort4 o; o.x = f2b(v0); o.y = f2b(v1); o.z = f2b(v2); o.w = f2b(v3);
            *(ushort4*)(hb + base) = o;
            if (stage) {
                int row = (base >> 7) - lb * 32;
                *(ushort4*)(crow_s + row * 136 + (base & 127)) = o;
            }
        }
    }
    if (stage) {
        __syncthreads();
        int lane = t & 63, w = t >> 6;
        int r = lane & 15, q = lane >> 4;
        int rg = w & 1;
        const unsigned short* ap = crow_s + (rg * 16 + r) * 136 + q * 8;
        bf16x8 afrag[4];
#pragma unroll
        for (int kc = 0; kc < 4; ++kc)
            afrag[kc] = *(const bf16x8*)(const void*)(ap + kc * 32);
        int t0 = (w >> 1) * 12;
        for (int tt = t0; tt < t0 + 12; ++tt) {
            f32x4 acc = {0.f, 0.f, 0.f, 0.f};
#pragma unroll
            for (int kc = 0; kc < 4; ++kc) {
                bf16x8 bfrag = *(const bf16x8*)(const void*)(WinB + (((size_t)tt * 4 + kc) << 9) + lane * 8);
                acc = __builtin_amdgcn_mfma_f32_16x16x32_bf16(afrag[kc], bfrag, acc, 0, 0, 0);
            }
            int n0c = tt * 16;
            float bv = binb[n0c + r];
#pragma unroll
            for (int t4 = 0; t4 < 4; ++t4) {
                int row = lb * 32 + rg * 16 + q * 4 + t4;
                if (row < n) cqkv[(size_t)row * 384 + n0c + r] = acc[t4] + bv;
            }
        }
    }
}

// ---------------- fused L2-apply(node) + MHA + mean + res + LN + cls-W1 ------
// Block owns 16 rows. Phase 0: reduce node L2 bins, BN+ReLU+residual from
// agg/hb_old -> hb_s (LDS, stride 136; never written to global). Then the
// R16 mha pipeline reads A-frags and residual rows from hb_s.
__global__ __launch_bounds__(256) void mha_fused_kernel(
    const float* __restrict__ agg, const float* __restrict__ binsL2,
    const float* __restrict__ gbn, const float* __restrict__ bebn,
    const unsigned short* __restrict__ hbo, const int* __restrict__ map,
    const float* __restrict__ cqkv,
    const unsigned short* __restrict__ WinB, const float* __restrict__ bin,
    const unsigned short* __restrict__ WoutB, const float* __restrict__ bout,
    const float* __restrict__ lng, const float* __restrict__ lnb,
    const unsigned short* __restrict__ W1t, const float* __restrict__ b1v,
    float* __restrict__ z, float* __restrict__ zbins, int nN, int nC) {
    __shared__ float bs[256];
    __shared__ float sc_s[128], sh_s[128];
    __shared__ unsigned short hb_s[16 * 136];    // final node features (LDS only)
    __shared__ unsigned short obf_s[16 * 136];   // attn out; reused as hf_s
    __shared__ float att_s[16 * 132];

    int b = blockIdx.x;
    int t = threadIdx.x;
    int hg = t >> 6;
    int lane = t & 63;
    int r = lane & 15, q = lane >> 4;

    // ---- phase 0: node L2 BN-apply for this block's 16 rows ----
    {
        float a = 0.f;
#pragma unroll
        for (int b2 = 0; b2 < 32; ++b2) a += binsL2[b2 * 256 + t];
        bs[t] = a;
    }
    __syncthreads();
    if (t < 128) {
        float inv = 1.f / (float)nN;
        float mean = bs[t] * inv;
        float var = bs[128 + t] * inv - mean * mean;
        float rstd = rsqrtf(var + EPSV);
        float s = gbn[t] * rstd;
        sc_s[t] = s;
        sh_s[t] = bebn[t] - mean * s;
    }
    __syncthreads();
    {
        int base = b * 2048 + t * 8;   // 16 rows x 128 = 2048 floats; 8/thread
        if (base < nN * 128) {
            float4 a1 = *(const float4*)(agg + base);
            float4 a2 = *(const float4*)(agg + base + 4);
            ushort4 h1 = *(const ushort4*)(hbo + base);
            ushort4 h2 = *(const ushort4*)(hbo + base + 4);
            int f = base & 127;
            float v0 = fmaxf(a1.x * sc_s[f] + sh_s[f], 0.f) + b2f(h1.x);
            float v1 = fmaxf(a1.y * sc_s[f + 1] + sh_s[f + 1], 0.f) + b2f(h1.y);
            float v2 = fmaxf(a1.z * sc_s[f + 2] + sh_s[f + 2], 0.f) + b2f(h1.z);
            float v3 = fmaxf(a1.w * sc_s[f + 3] + sh_s[f + 3], 0.f) + b2f(h1.w);
            float v4 = fmaxf(a2.x * sc_s[f + 4] + sh_s[f + 4], 0.f) + b2f(h2.x);
            float v5 = fmaxf(a2.y * sc_s[f + 5] + sh_s[f + 5], 0.f) + b2f(h2.y);
            float v6 = fmaxf(a2.z * sc_s[f + 6] + sh_s[f + 6], 0.f) + b2f(h2.z);
            float v7 = fmaxf(a2.w * sc_s[f + 7] + sh_s[f + 7], 0.f) + b2f(h2.w);
            int lr = (base >> 7) - b * 16;
            ushort4 o1, o2;
            o1.x = f2b(v0); o1.y = f2b(v1); o1.z = f2b(v2); o1.w = f2b(v3);
            o2.x = f2b(v4); o2.y = f2b(v5); o2.z = f2b(v6); o2.w = f2b(v7);
            *(ushort4*)(hb_s + lr * 136 + f) = o1;
            *(ushort4*)(hb_s + lr * 136 + f + 4) = o2;
        }
    }
    __syncthreads();

    // ---- A-fragment from LDS hb_s ----
    int arow = b * 16 + r; if (arow >= nN) arow = nN - 1;
    const unsigned short* ap = hb_s + (arow - b * 16) * 136 + q * 8;
    bf16x8 afrag[4];
#pragma unroll
    for (int kc = 0; kc < 4; ++kc)
        afrag[kc] = *(const bf16x8*)(const void*)(ap + kc * 32);

    // comm-QKV base pointers for this lane's 4 output rows (q*4+t)
    const float* cp[4];
#pragma unroll
    for (int tt4 = 0; tt4 < 4; ++tt4) {
        int nt = b * 16 + q * 4 + tt4; if (nt >= nN) nt = nN - 1;
        int c = map[nt]; c = c < 0 ? 0 : (c >= nC ? nC - 1 : c);
        cp[tt4] = cqkv + (size_t)c * 384;
    }

#pragma unroll
    for (int c = 0; c < 2; ++c) {
        int h = hg * 2 + c;
        f32x4 qa, ka, va;
#pragma unroll
        for (int p = 0; p < 3; ++p) {
            int tt = p * 8 + h;
            f32x4 acc = {0.f, 0.f, 0.f, 0.f};
#pragma unroll
            for (int kc = 0; kc < 4; ++kc) {
                bf16x8 bfrag = *(const bf16x8*)(const void*)(WinB + (((size_t)tt * 4 + kc) << 9) + lane * 8);
                acc = __builtin_amdgcn_mfma_f32_16x16x32_bf16(afrag[kc], bfrag, acc, 0, 0, 0);
            }
            float bv = bin[tt * 16 + r];
#pragma unroll
            for (int t4 = 0; t4 < 4; ++t4) acc[t4] += bv;
            if (p == 0) qa = acc; else if (p == 1) ka = acc; else va = acc;
        }
        float qc[4], kc_[4], vc[4];
#pragma unroll
        for (int t4 = 0; t4 < 4; ++t4) {
            const float* cpt = cp[t4] + h * 16 + r;
            qc[t4] = cpt[0]; kc_[t4] = cpt[128]; vc[t4] = cpt[256];
        }
#pragma unroll
        for (int t4 = 0; t4 < 4; ++t4) {
            float s00 = qa[t4] * ka[t4];
            float s01 = qa[t4] * kc_[t4];
            float s10 = qc[t4] * ka[t4];
            float s11 = qc[t4] * kc_[t4];
#pragma unroll
            for (int mku = 1; mku <= 8; mku <<= 1) {
                s00 += __shfl_xor(s00, mku); s01 += __shfl_xor(s01, mku);
                s10 += __shfl_xor(s10, mku); s11 += __shfl_xor(s11, mku);
            }
            s00 *= 0.25f; s01 *= 0.25f; s10 *= 0.25f; s11 *= 0.25f;
            float m0 = fmaxf(s00, s01), m1 = fmaxf(s10, s11);
            float e00 = __expf(s00 - m0), e01 = __expf(s01 - m0);
            float e10 = __expf(s10 - m1), e11 = __expf(s11 - m1);
            float i0 = 1.f / (e00 + e01), i1 = 1.f / (e10 + e11);
            float o0 = (e00 * va[t4] + e01 * vc[t4]) * i0;
            float o1 = (e10 * va[t4] + e11 * vc[t4]) * i1;
            obf_s[(q * 4 + t4) * 136 + h * 16 + r] = f2b(0.5f * (o0 + o1));
        }
    }
    __syncthreads();

    // ---- out-proj on mean rows; wave hg handles tiles {2hg, 2hg+1} ----
    bf16x8 ofrag[4];
#pragma unroll
    for (int kc = 0; kc < 4; ++kc)
        ofrag[kc] = *(const bf16x8*)(const void*)(obf_s + r * 136 + q * 8 + kc * 32);
#pragma unroll
    for (int c = 0; c < 2; ++c) {
        int tt = hg * 2 + c;
        f32x4 acc = {0.f, 0.f, 0.f, 0.f};
#pragma unroll
        for (int kc = 0; kc < 4; ++kc) {
            bf16x8 bfrag = *(const bf16x8*)(const void*)(WoutB + (((size_t)tt * 4 + kc) << 9) + lane * 8);
            acc = __builtin_amdgcn_mfma_f32_16x16x32_bf16(ofrag[kc], bfrag, acc, 0, 0, 0);
        }
        int n0 = tt * 16;
        float bv = bout[n0 + r];
#pragma unroll
        for (int t4 = 0; t4 < 4; ++t4)
            att_s[(q * 4 + t4) * 132 + n0 + r] = acc[t4] + bv;
    }
    __syncthreads();
    unsigned short* hf_s = obf_s;

    // ---- residual + LayerNorm (16 lanes per node, 8 cols each) -> LDS ----
    {
        int nl = t >> 4;
        int j = t & 15;
        int gnode = b * 16 + nl;
        if (gnode >= nN) gnode = nN - 1;
        const unsigned short* hrow = hb_s + (gnode - b * 16) * 136 + j * 8;
        ushort4 ha = *(const ushort4*)(hrow);
        ushort4 hbv = *(const ushort4*)(hrow + 4);
        float x[8]; float s = 0.f, s2 = 0.f;
        x[0] = att_s[nl * 132 + j * 8 + 0] + b2f(ha.x);
        x[1] = att_s[nl * 132 + j * 8 + 1] + b2f(ha.y);
        x[2] = att_s[nl * 132 + j * 8 + 2] + b2f(ha.z);
        x[3] = att_s[nl * 132 + j * 8 + 3] + b2f(ha.w);
        x[4] = att_s[nl * 132 + j * 8 + 4] + b2f(hbv.x);
        x[5] = att_s[nl * 132 + j * 8 + 5] + b2f(hbv.y);
        x[6] = att_s[nl * 132 + j * 8 + 6] + b2f(hbv.z);
        x[7] = att_s[nl * 132 + j * 8 + 7] + b2f(hbv.w);
#pragma unroll
        for (int i = 0; i < 8; ++i) { s += x[i]; s2 += x[i] * x[i]; }
        s += __shfl_xor(s, 1);  s2 += __shfl_xor(s2, 1);
        s += __shfl_xor(s, 2);  s2 += __shfl_xor(s2, 2);
        s += __shfl_xor(s, 4);  s2 += __shfl_xor(s2, 4);
        s += __shfl_xor(s, 8);  s2 += __shfl_xor(s2, 8);
        float mu = s * (1.f / 128.f);
        float var = s2 * (1.f / 128.f) - mu * mu;
        float rstd = rsqrtf(var + EPSV);
        ushort4 o1, o2;
        o1.x = f2b((x[0] - mu) * rstd * lng[j * 8 + 0] + lnb[j * 8 + 0]);
        o1.y = f2b((x[1] - mu) * rstd * lng[j * 8 + 1] + lnb[j * 8 + 1]);
        o1.z = f2b((x[2] - mu) * rstd * lng[j * 8 + 2] + lnb[j * 8 + 2]);
        o1.w = f2b((x[3] - mu) * rstd * lng[j * 8 + 3] + lnb[j * 8 + 3]);
        o2.x = f2b((x[4] - mu) * rstd * lng[j * 8 + 4] + lnb[j * 8 + 4]);
        o2.y = f2b((x[5] - mu) * rstd * lng[j * 8 + 5] + lnb[j * 8 + 5]);
        o2.z = f2b((x[6] - mu) * rstd * lng[j * 8 + 6] + lnb[j * 8 + 6]);
        o2.w = f2b((x[7] - mu) * rstd * lng[j * 8 + 7] + lnb[j * 8 + 7]);
        *(ushort4*)(hf_s + nl * 136 + j * 8) = o1;
        *(ushort4*)(hf_s + nl * 136 + j * 8 + 4) = o2;
    }
    __syncthreads();

    // ---- classifier W1 tile: wave hg -> cols [hg*16, hg*16+16) of z ----
    {
        bf16x8 hfrag[4];
#pragma unroll
        for (int kc = 0; kc < 4; ++kc)
            hfrag[kc] = *(const bf16x8*)(const void*)(hf_s + r * 136 + q * 8 + kc * 32);
        f32x4 acc = {0.f, 0.f, 0.f, 0.f};
#pragma unroll
        for (int kc = 0; kc < 4; ++kc) {
            bf16x8 bfrag = *(const bf16x8*)(const void*)(W1t + (((size_t)hg * 4 + kc) << 9) + lane * 8);
            acc = __builtin_amdgcn_mfma_f32_16x16x32_bf16(hfrag[kc], bfrag, acc, 0, 0, 0);
        }
        float bv = b1v[hg * 16 + r];
        float s = 0.f, s2 = 0.f;
#pragma unroll
        for (int t4 = 0; t4 < 4; ++t4) {
            int row = b * 16 + q * 4 + t4;
            if (row < nN) {
                float v = acc[t4] + bv;
                z[(size_t)row * 64 + hg * 16 + r] = v;
                s += v; s2 += v * v;
            }
        }
        s += __shfl_xor(s, 16);  s2 += __shfl_xor(s2, 16);
        s += __shfl_xor(s, 32);  s2 += __shfl_xor(s2, 32);
        if (lane < 16) {
            int bb = (b & 31) * 128;
            atomicAdd(&zbins[bb + hg * 16 + r], s);
            atomicAdd(&zbins[bb + 64 + hg * 16 + r], s2);
        }
    }
}

// ---------------- final: BN(inline zbins reduce)+ReLU+Linear(64,10)+lsm ------
__global__ __launch_bounds__(256) void final_kernel(const float* __restrict__ z,
                                                    const float* __restrict__ zbins,
                                                    const float* __restrict__ g,
                                                    const float* __restrict__ be,
                                                    const float* __restrict__ W2,
                                                    const float* __restrict__ b2v,
                                                    float* __restrict__ out, int nN) {
    __shared__ float zs[128];
    int t = threadIdx.x;
    if (t < 128) {
        float a = 0.f;
#pragma unroll
        for (int b = 0; b < 32; ++b) a += zbins[b * 128 + t];
        zs[t] = a;
    }
    __syncthreads();
    int lane = t & 63;
    float inv = 1.f / (float)nN;
    float mean = zs[lane] * inv;
    float var = zs[64 + lane] * inv - mean * mean;
    float sc = g[lane] * rsqrtf(var + EPSV);
    float sh = be[lane] - mean * sc;
    const float* wrow = W2 + lane * 10;
#pragma unroll
    for (int it = 0; it < 4; ++it) {
        int node = blockIdx.x * 16 + (t >> 6) * 4 + it;
        float v = 0.f;
        if (node < nN) v = fmaxf(z[(size_t)node * 64 + lane] * sc + sh, 0.f);
        float p[10];
#pragma unroll
        for (int c = 0; c < 10; ++c) p[c] = v * wrow[c];
#pragma unroll
        for (int off = 32; off >= 1; off >>= 1) {
#pragma unroll
            for (int c = 0; c < 10; ++c) p[c] += __shfl_xor(p[c], off);
        }
        if (node < nN) {
            float l[10], mx = -1e30f;
#pragma unroll
            for (int c = 0; c < 10; ++c) { l[c] = p[c] + b2v[c]; mx = fmaxf(mx, l[c]); }
            float se = 0.f;
#pragma unroll
            for (int c = 0; c < 10; ++c) se += expf(l[c] - mx);
            float lse = mx + logf(se);
            if (lane < 10) out[(size_t)node * 10 + lane] = l[lane] - lse;
        }
    }
}

// ---------------------------------------------------------------------------
static inline int cdiv(long a, long b) { return (int)((a + b - 1) / b); }

extern "C" void kernel_launch(void* const* d_in, const int* in_sizes, int n_in,
                              void* d_out, int out_size, void* d_ws, size_t ws_size,
                              hipStream_t stream) {
    const float* node_feat = (const float*)d_in[0];
    const int*   nedge     = (const int*)d_in[1];
    const float* comm_feat = (const float*)d_in[2];
    const int*   cedge     = (const int*)d_in[3];
    const int*   n2c       = (const int*)d_in[4];
    const float* node_W    = (const float*)d_in[5];
    const float* node_b    = (const float*)d_in[6];
    const float* node_g    = (const float*)d_in[7];
    const float* node_beta = (const float*)d_in[8];
    const float* comm_W    = (const float*)d_in[9];
    const float* comm_b    = (const float*)d_in[10];
    const float* comm_g    = (const float*)d_in[11];
    const float* comm_beta = (const float*)d_in[12];
    const float* attn_in_w = (const float*)d_in[13];
    const float* attn_in_b = (const float*)d_in[14];
    const float* attn_out_w= (const float*)d_in[15];
    const float* attn_out_b= (const float*)d_in[16];
    const float* ln_g      = (const float*)d_in[17];
    const float* ln_b      = (const float*)d_in[18];
    const float* cls_W1    = (const float*)d_in[19];
    const float* cls_b1    = (const float*)d_in[20];
    const float* cls_bn_g  = (const float*)d_in[21];
    const float* cls_bn_b  = (const float*)d_in[22];
    const float* cls_W2    = (const float*)d_in[23];
    const float* cls_b2    = (const float*)d_in[24];

    const int nN = in_sizes[0] / 128;
    const int nE = in_sizes[1] / 2;
    const int nC = in_sizes[2] / 128;
    const int cE = in_sizes[3] / 2;
    const int padE_n = nE + 8 * nN;
    const int padE_c = cE + 8 * nC;

    char* ws = (char*)d_ws;
    size_t off = 0;
    auto alloc = [&](size_t bytes) -> char* {
        char* p = ws + off;
        off = (off + bytes + 255) & ~(size_t)255;
        return p;
    };
    // ---- contiguous zero region (single memset; includes csrc: 0 = pad) ----
    size_t zero_begin = off;
    int*   cnt_n  = (int*)alloc((size_t)nN * 4);
    int*   cur_n  = (int*)alloc((size_t)nN * 4);
    int*   cnt_c  = (int*)alloc((size_t)nC * 4);
    int*   cur_c  = (int*)alloc((size_t)nC * 4);
    float* bins_n = (float*)alloc((size_t)3 * 32 * 256 * 4);  // per-layer
    float* bins_c = (float*)alloc((size_t)3 * 32 * 256 * 4);  // per-layer
    float* zbins  = (float*)alloc((size_t)32 * 128 * 4);
    unsigned short* csrc_n = (unsigned short*)alloc((size_t)padE_n * 2);
    unsigned short* csrc_c = (unsigned short*)alloc((size_t)padE_c * 2);
    size_t zero_bytes = off - zero_begin;
    // ---- CSR aux ----
    int*   rs_n   = (int*)alloc((size_t)(nN + 1) * 4);
    int*   bsum_n = (int*)alloc(256 * 4);
    float* dinv_n = (float*)alloc((size_t)nN * 4);
    int*   rs_c   = (int*)alloc((size_t)(nC + 1) * 4);
    int*   bsum_c = (int*)alloc(256 * 4);
    float* dinv_c = (float*)alloc((size_t)nC * 4);
    // ---- activations / weights ----
    unsigned short* hb_n  = (unsigned short*)alloc((size_t)nN * 256);
    unsigned short* hb_c  = (unsigned short*)alloc((size_t)nC * 256);
    unsigned short* cfb   = (unsigned short*)alloc((size_t)nC * 256);
    unsigned short* m_cb  = (unsigned short*)alloc((size_t)nC * 256);
    float*          agg_c = (float*)alloc((size_t)nC * 512);
    float*          cqkv  = (float*)alloc((size_t)nC * 384 * 4);
    unsigned short* WtN  = (unsigned short*)alloc((size_t)3 * 16384 * 2);
    unsigned short* WtC  = (unsigned short*)alloc((size_t)3 * 16384 * 2);
    unsigned short* W1t  = (unsigned short*)alloc((size_t)64 * 128 * 2);
    unsigned short* WinB = (unsigned short*)alloc((size_t)384 * 128 * 2);
    unsigned short* WoutB= (unsigned short*)alloc((size_t)128 * 128 * 2);
    unsigned short* m_nb = (unsigned short*)alloc((size_t)nN * 256);
    float*          agg_n= (float*)alloc((size_t)nN * 512);
    // aliases (disjoint liveness)
    unsigned short* nfb  = (unsigned short*)agg_n;
    float*          z    = (float*)m_nb;   // m_nb free after gather L2 (z: nN*64*4 = nN*256 bytes, fits)

    hipMemsetAsync(ws + zero_begin, 0, zero_bytes, stream);

    // ---- prep (+ edge-degree count, 4 edges/thread, as trailing blocks) ----
    long prepN = 49152L * 3 + 8192 + 16384 + (long)nC * 128 + (long)nN * 128;
    long cntThreads = ((long)nE + cE + 3) / 4;
    long prepTotal = prepN + cntThreads;
    prep_kernel<<<cdiv(prepTotal, 256), 256, 0, stream>>>(
        node_W, comm_W, cls_W1, attn_in_w, attn_out_w, comm_feat, node_feat,
        WtN, WtC, W1t, WinB, WoutB, cfb, nfb, nC * 128, nN * 128,
        nedge + nE, cnt_n, nE, cedge + cE, cnt_c, cE);

    // ---- CSR scan (rows padded to x8) ----
    int nbN = cdiv(nN, 1024), nbC = cdiv(nC, 1024);
    int dinvB = cdiv((long)nN + nC, 1024);
    scan_block_dual<<<nbN + nbC + dinvB, 1024, 0, stream>>>(
        cnt_n, rs_n, bsum_n, nN, nbN, cnt_c, rs_c, bsum_c, nC, dinv_n, dinv_c);
    scan_add_dual<<<cdiv((long)nN + nC, 256), 256, 0, stream>>>(
        rs_n, bsum_n, cur_n, nN, rs_c, bsum_c, cur_c, nC);

    // ---- GCN layers ----
    int gemmA = cdiv(nN, 64), gemmB = cdiv(nC, 64);
    int fillB = cdiv((long)nE + cE, 1024);   // 4 edges/thread
    int gatA = cdiv(nN, 4), gatB = cdiv(nC, 4);
    int appB = cdiv((long)nC * 128, 4096);

    // L0 gemm + CSR fill (independent work, one dispatch)
    gemm_fill_kernel<<<gemmA + gemmB + fillB, 256, 0, stream>>>(
        nfb, WtN, dinv_n, m_nb, nN, gemmA,
        cfb, WtC, dinv_c, m_cb, nC, gemmB,
        nedge, nedge + nE, cur_n, csrc_n, nE,
        cedge, cedge + cE, cur_c, csrc_c, cE);
    // gather L0
    gather_dual<<<gatA + gatB, 256, 0, stream>>>(
        m_nb, rs_n, cnt_n, csrc_n, dinv_n, node_b, agg_n, bins_n, nN, gatA,
        m_cb, rs_c, cnt_c, csrc_c, dinv_c, comm_b, agg_c, bins_c, nC);
    // apply L0 + gemm L1 (fused)
    applygemm_dual<<<gemmA + gemmB, 256, 0, stream>>>(
        agg_n, bins_n, node_g, node_beta, hb_n, WtN + 16384, dinv_n, m_nb, nN, gemmA, 0,
        agg_c, bins_c, comm_g, comm_beta, hb_c, WtC + 16384, dinv_c, m_cb, nC);
    // gather L1
    gather_dual<<<gatA + gatB, 256, 0, stream>>>(
        m_nb, rs_n, cnt_n, csrc_n, dinv_n, node_b + 128, agg_n, bins_n + 32 * 256, nN, gatA,
        m_cb, rs_c, cnt_c, csrc_c, dinv_c, comm_b + 128, agg_c, bins_c + 32 * 256, nC);
    // apply L1 + gemm L2 (fused)
    applygemm_dual<<<gemmA + gemmB, 256, 0, stream>>>(
        agg_n, bins_n + 32 * 256, node_g + 128, node_beta + 128, hb_n, WtN + 2 * 16384, dinv_n, m_nb, nN, gemmA, 1,
        agg_c, bins_c + 32 * 256, comm_g + 128, comm_beta + 128, hb_c, WtC + 2 * 16384, dinv_c, m_cb, nC);
    // gather L2
    gather_dual<<<gatA + gatB, 256, 0, stream>>>(
        m_nb, rs_n, cnt_n, csrc_n, dinv_n, node_b + 256, agg_n, bins_n + 2 * 32 * 256, nN, gatA,
        m_cb, rs_c, cnt_c, csrc_c, dinv_c, comm_b + 256, agg_c, bins_c + 2 * 32 * 256, nC);
    // apply L2: COMM ONLY (blocksA = 0) + inline comm QKV projection -> cqkv
    apply_dual<<<appB, 256, 0, stream>>>(
        agg_n, bins_n + 2 * 32 * 256, node_g + 256, node_beta + 256, hb_n, nN, 0, 1,
        agg_c, bins_c + 2 * 32 * 256, comm_g + 256, comm_beta + 256, hb_c, nC,
        1, WinB, attn_in_b, cqkv);

    // ---- fused node-L2-apply + MHA + mean + residual + LN + cls-W1 ----
    mha_fused_kernel<<<cdiv(nN, 16), 256, 0, stream>>>(
        agg_n, bins_n + 2 * 32 * 256, node_g + 256, node_beta + 256,
        hb_n, n2c, cqkv, WinB, attn_in_b, WoutB, attn_out_b, ln_g, ln_b,
        W1t, cls_b1, z, zbins, nN, nC);

    // ---- classifier tail (zbins reduced inline per block) ----
    final_kernel<<<cdiv(nN, 16), 256, 0, stream>>>(
        z, zbins, cls_bn_g, cls_bn_b, cls_W2, cls_b2, (float*)d_out, nN);
}